// Round 3
// baseline (401.432 us; speedup 1.0000x reference)
//
#include <hip/hip_runtime.h>

#define S_LEN 2048
#define HEADS 16
#define DIM 64

typedef __attribute__((ext_vector_type(8))) short short8;
typedef __attribute__((ext_vector_type(16))) float float16v;
typedef __attribute__((ext_vector_type(4))) float float4v;
typedef __attribute__((ext_vector_type(4))) unsigned uint4v;

// packed fp32x2 -> bf16x2 (RNE), lo = first arg
static __device__ __forceinline__ unsigned pkbf(float lo, float hi) {
  unsigned r;
  asm("v_cvt_pk_bf16_f32 %0, %1, %2" : "=v"(r) : "v"(lo), "v"(hi));
  return r;
}

// ---------------- prep ----------------
// K: fp32 [bh][j][f] -> bf16, stored in MFMA-A-fragment order per 32-key tile:
//    kb[bh][jt][ks][hf][n][e]  (shorts: jt*2048 + ks*512 + hf*256 + n*8 + e)
//    holding K[jt*32+n][16ks+8hf+e] -- attn loads a tile as 4 contiguous 1KB chunks.
// V: fp32 [bh][j][f] -> bf16 V^T with bit2<->3 j-permute (matches P^T register
//    layout), stored fragment-ordered per 32-key tile:
//    vt[bh][jt][q=fh*2+kc][hf][n][e] holding V^T[f=fh*32+n][p=kc*16+8hf+e]
__global__ __launch_bounds__(256) void prep(const float* __restrict__ kk,
                                            const float* __restrict__ vv,
                                            short* __restrict__ kb,
                                            short* __restrict__ vt) {
  __shared__ unsigned t32[64 * 33];  // [f][p2] u32 = bf16 pair (p even, p odd)
  const int bx = blockIdx.x;
  const int bh = bx >> 5;
  const int j0 = (bx & 31) * 64;
  const int tid = threadIdx.x;

  // K convert -> fragment-ordered
  {
    const int j = tid >> 2, f0 = (tid & 3) * 16;
    const float4v* src = (const float4v*)(kk + ((size_t)bh * S_LEN + j0 + j) * DIM + f0);
    float4v a0 = src[0], a1 = src[1], a2 = src[2], a3 = src[3];
    uint4v w0, w1;
    w0[0] = pkbf(a0[0], a0[1]); w0[1] = pkbf(a0[2], a0[3]);
    w0[2] = pkbf(a1[0], a1[1]); w0[3] = pkbf(a1[2], a1[3]);
    w1[0] = pkbf(a2[0], a2[1]); w1[1] = pkbf(a2[2], a2[3]);
    w1[2] = pkbf(a3[0], a3[1]); w1[3] = pkbf(a3[2], a3[3]);
    short* dstb = kb + (size_t)bh * (S_LEN * DIM) +
                  ((j0 >> 5) + (j >> 5)) * 2048 + (f0 >> 4) * 512 + (j & 31) * 8;
    *(uint4v*)dstb = w0;            // hf = 0 chunk (f0..f0+7)
    *(uint4v*)(dstb + 256) = w1;    // hf = 1 chunk (f0+8..f0+15)
  }
  // V transpose + bit2<->3 permute; pack adjacent-j pairs
  {
    const int jp = (tid & 31) * 2, f0 = (tid >> 5) * 8;
    const int pp = ((jp & ~12) | ((jp & 4) << 1) | ((jp & 8) >> 1)) >> 1;
    const float* r0 = vv + ((size_t)bh * S_LEN + j0 + jp) * DIM + f0;
    const float* r1 = r0 + DIM;
    float4v a0 = *(const float4v*)r0, a1 = *(const float4v*)(r0 + 4);
    float4v b0 = *(const float4v*)r1, b1 = *(const float4v*)(r1 + 4);
#pragma unroll
    for (int e = 0; e < 4; e++) {
      t32[(f0 + e) * 33 + pp]     = pkbf(a0[e], b0[e]);
      t32[(f0 + 4 + e) * 33 + pp] = pkbf(a1[e], b1[e]);
    }
  }
  __syncthreads();
  {
    const int f = tid >> 2, x0 = (tid & 3) * 8;
    uint4v c0 = *(const uint4v*)&t32[f * 33 + x0];       // p = 2*x0 .. 2*x0+7  (hf=0)
    uint4v c1 = *(const uint4v*)&t32[f * 33 + x0 + 4];   // p = 2*x0+8 .. +15   (hf=1)
    const int jt = (j0 >> 5) + (x0 >> 4);
    const int qd = (f >> 5) * 2 + ((x0 >> 3) & 1);       // fh*2 + kc
    short* dstb = vt + (size_t)bh * (S_LEN * DIM) + jt * 2048 + qd * 512 + (f & 31) * 8;
    *(uint4v*)dstb = c0;
    *(uint4v*)(dstb + 256) = c1;
  }
}

// ---------------- fused attention: barrier-free 4-way j-split ----------------
// grid 1024 = 32 bh * 32 i-tiles(64 rows); block 256 = 4 waves.
// Wave w handles ALL 64 i-rows for a QUARTER of the keys (j in [w*512, w*512+512)),
// 16 iterations of 32-key tiles. No LDS / no barriers in the main loop; K/V frags
// load straight global->VGPR from fragment-ordered tiles; register prefetch 1 tile
// ahead. 16 waves/CU (4 blocks x 4 waves) -> 4 waves/SIMD hides the chain latency.
// Epilogue: 3-round ring reduction of quadrant partials + denom combine via LDS.
__global__ __launch_bounds__(256, 4) void attn_fwd(const float* __restrict__ q,
                                                   const short* __restrict__ kb,
                                                   const short* __restrict__ vt,
                                                   float* __restrict__ out) {
  __shared__ alignas(16) float smem[4 * 1056 + 256];  // 4 slots (ring/transpose) + denom
  const int bx0 = blockIdx.x;
  const int bx = (bx0 & 7) * 128 + (bx0 >> 3);  // XCD-chunked swizzle (bijective, 1024%8==0)
  const int bh = bx >> 5, it = bx & 31;
  const int b = bh >> 4, h = bh & 15;
  const int tid = threadIdx.x;
  const int w = tid >> 6, lane = tid & 63;
  const int n = lane & 31, hf = lane >> 5;
  const int i0 = it * 64;

  // Q B-frags for two i-tiles (cols i0+n and i0+32+n), scaled by log2e/8
  short8 qa0[4], qa1[4];
  {
    const float sc = 0.125f * 1.44269504088896f;
    const float* qr = q + ((size_t)bh * S_LEN + i0 + n) * DIM + hf * 8;
#pragma unroll
    for (int ks = 0; ks < 4; ks++) {
      float4v x0 = *(const float4v*)(qr + ks * 16);
      float4v x1 = *(const float4v*)(qr + ks * 16 + 4);
      uint4v pk_;
      pk_[0] = pkbf(x0[0] * sc, x0[1] * sc); pk_[1] = pkbf(x0[2] * sc, x0[3] * sc);
      pk_[2] = pkbf(x1[0] * sc, x1[1] * sc); pk_[3] = pkbf(x1[2] * sc, x1[3] * sc);
      qa0[ks] = *(short8*)&pk_;
      float4v y0 = *(const float4v*)(qr + 32 * DIM + ks * 16);
      float4v y1 = *(const float4v*)(qr + 32 * DIM + ks * 16 + 4);
      pk_[0] = pkbf(y0[0] * sc, y0[1] * sc); pk_[1] = pkbf(y0[2] * sc, y0[3] * sc);
      pk_[2] = pkbf(y1[0] * sc, y1[1] * sc); pk_[3] = pkbf(y1[2] * sc, y1[3] * sc);
      qa1[ks] = *(short8*)&pk_;
    }
  }

  // per-lane tile base pointers (this wave's j-quarter; tile = 2048 shorts = 4KB)
  const short* kp = kb + (size_t)bh * (S_LEN * DIM) + (size_t)w * (S_LEN * DIM / 4) + lane * 8;
  const short* vp = vt + (size_t)bh * (S_LEN * DIM) + (size_t)w * (S_LEN * DIM / 4) + lane * 8;

  short8 kf[4], vf[4];
#pragma unroll
  for (int u = 0; u < 4; u++) {
    kf[u] = *(const short8*)(kp + u * 512);
    vf[u] = *(const short8*)(vp + u * 512);
  }

  float16v zz;
#pragma unroll
  for (int e = 0; e < 16; e++) zz[e] = 0.f;
  float16v a00 = zz, a01 = zz, a10 = zz, a11 = zz;  // a[fh][itile] of O^T (unnormalized)
  float lpa0 = 0.f, lpb0 = 0.f, lpa1 = 0.f, lpb1 = 0.f;  // split add-chains

#pragma unroll 1
  for (int t = 0; t < 16; ++t) {
    const int adv = (t < 15) ? 2048 : 0;
    // S^T = K (Q')^T : rows j (reg), cols i (lane)
    __builtin_amdgcn_s_setprio(1);
    float16v st0 = __builtin_amdgcn_mfma_f32_32x32x16_bf16(kf[0], qa0[0], zz, 0, 0, 0);
    float16v st1 = __builtin_amdgcn_mfma_f32_32x32x16_bf16(kf[0], qa1[0], zz, 0, 0, 0);
#pragma unroll
    for (int ks = 1; ks < 4; ks++) {
      st0 = __builtin_amdgcn_mfma_f32_32x32x16_bf16(kf[ks], qa0[ks], st0, 0, 0, 0);
      st1 = __builtin_amdgcn_mfma_f32_32x32x16_bf16(kf[ks], qa1[ks], st1, 0, 0, 0);
    }
    __builtin_amdgcn_s_setprio(0);
    // prefetch K(t+1) -- kf consumed above, loads fly under exp/pack/PV
    kp += adv;
#pragma unroll
    for (int u = 0; u < 4; u++) kf[u] = *(const short8*)(kp + u * 512);

    // exp2 + denom partials + pack P^T to bf16
#pragma unroll
    for (int e = 0; e < 16; e++) {
      st0[e] = __builtin_amdgcn_exp2f(st0[e]);
      st1[e] = __builtin_amdgcn_exp2f(st1[e]);
    }
#pragma unroll
    for (int e = 0; e < 8; e++) {
      lpa0 += st0[2 * e]; lpb0 += st0[2 * e + 1];
      lpa1 += st1[2 * e]; lpb1 += st1[2 * e + 1];
    }
    uint4v pb00, pb01, pb10, pb11;
#pragma unroll
    for (int u = 0; u < 4; u++) {
      pb00[u] = pkbf(st0[2 * u], st0[2 * u + 1]);
      pb01[u] = pkbf(st0[8 + 2 * u], st0[8 + 2 * u + 1]);
      pb10[u] = pkbf(st1[2 * u], st1[2 * u + 1]);
      pb11[u] = pkbf(st1[8 + 2 * u], st1[8 + 2 * u + 1]);
    }
    short8 p00 = *(short8*)&pb00, p01 = *(short8*)&pb01;
    short8 p10 = *(short8*)&pb10, p11 = *(short8*)&pb11;

    // O^T += V^T P^T  (vf[q]: q = fh*2+kc)
    __builtin_amdgcn_s_setprio(1);
    a00 = __builtin_amdgcn_mfma_f32_32x32x16_bf16(vf[0], p00, a00, 0, 0, 0);
    a00 = __builtin_amdgcn_mfma_f32_32x32x16_bf16(vf[1], p01, a00, 0, 0, 0);
    a01 = __builtin_amdgcn_mfma_f32_32x32x16_bf16(vf[0], p10, a01, 0, 0, 0);
    a01 = __builtin_amdgcn_mfma_f32_32x32x16_bf16(vf[1], p11, a01, 0, 0, 0);
    a10 = __builtin_amdgcn_mfma_f32_32x32x16_bf16(vf[2], p00, a10, 0, 0, 0);
    a10 = __builtin_amdgcn_mfma_f32_32x32x16_bf16(vf[3], p01, a10, 0, 0, 0);
    a11 = __builtin_amdgcn_mfma_f32_32x32x16_bf16(vf[2], p10, a11, 0, 0, 0);
    a11 = __builtin_amdgcn_mfma_f32_32x32x16_bf16(vf[3], p11, a11, 0, 0, 0);
    __builtin_amdgcn_s_setprio(0);
    // prefetch V(t+1)
    vp += adv;
#pragma unroll
    for (int u = 0; u < 4; u++) vf[u] = *(const short8*)(vp + u * 512);
  }

  // wave-local denominator (lanes n / n+32 hold complementary j rows of i = n)
  float d0 = lpa0 + lpb0;
  float d1 = lpa1 + lpb1;
  d0 += __shfl_xor(d0, 32);
  d1 += __shfl_xor(d1, 32);

  // ---- cross-wave combine: quadrant q = itile*2 + fh, wave w owns quadrant w ----
  // partials: pq[0]=a00 (it0,fh0)  pq[1]=a10 (it0,fh1)  pq[2]=a01 (it1,fh0)  pq[3]=a11 (it1,fh1)
  float* const slots = smem;              // 4 x 1056 floats (ring exchange, then transpose)
  float* const db = smem + 4 * 1056;      // [wave][itile][n] denominators

  if (hf == 0) { db[w * 64 + n] = d0; db[w * 64 + 32 + n] = d1; }

  float16v own = (w == 0) ? a00 : (w == 1) ? a10 : (w == 2) ? a01 : a11;
#pragma unroll
  for (int r = 1; r < 4; r++) {
    const int s = (w + r) & 3;
    float16v snd = (s == 0) ? a00 : (s == 1) ? a10 : (s == 2) ? a01 : a11;
    float* sl = slots + w * 1056;
#pragma unroll
    for (int c = 0; c < 4; c++) {
      float4v u;
#pragma unroll
      for (int e = 0; e < 4; e++) u[e] = snd[4 * c + e];
      *(float4v*)&sl[c * 256 + lane * 4] = u;
    }
    __syncthreads();
    const float* rl = slots + ((w - r) & 3) * 1056;
#pragma unroll
    for (int c = 0; c < 4; c++) {
      float4v u = *(const float4v*)&rl[c * 256 + lane * 4];
#pragma unroll
      for (int e = 0; e < 4; e++) own[4 * c + e] += u[e];
    }
    __syncthreads();
  }

  // total denominator for this wave's quadrant (itile = w>>1), column i = n
  const int myit = w >> 1;
  const float dt = db[myit * 32 + n] + db[64 + myit * 32 + n] +
                   db[128 + myit * 32 + n] + db[192 + myit * 32 + n];
  const float inv = 1.f / dt;

  // normalize + transpose own quadrant via per-wave LDS region, then store
  float* const tb = slots + w * 1056;  // [i_local][f_local] stride 33
#pragma unroll
  for (int c = 0; c < 4; c++) {
    float4v u;
#pragma unroll
    for (int e = 0; e < 4; e++) u[e] = own[4 * c + e] * inv;
    *(float4v*)&tb[n * 33 + 8 * c + 4 * hf] = u;  // f_local = 8c + 4hf + e
  }
  // within-wave LDS dependency only (disjoint per-wave regions): compiler inserts lgkmcnt
  {
    const int il = lane >> 1, fq2 = (lane & 1) * 16;
    const float* src = &tb[il * 33 + fq2];
    float* dst = out + (((size_t)b * S_LEN + i0 + myit * 32 + il) * HEADS + h) * DIM +
                 (w & 1) * 32 + fq2;
#pragma unroll
    for (int u = 0; u < 4; u++) ((float4v*)dst)[u] = ((const float4v*)src)[u];
  }
}

extern "C" void kernel_launch(void* const* d_in, const int* in_sizes, int n_in,
                              void* d_out, int out_size, void* d_ws, size_t ws_size,
                              hipStream_t stream) {
  const float* q = (const float*)d_in[0];
  const float* k = (const float*)d_in[1];
  const float* v = (const float*)d_in[2];
  float* out = (float*)d_out;
  short* kb = (short*)d_ws;                             // 8 MiB bf16 K (fragment-ordered)
  short* vt = (short*)d_ws + (size_t)32 * S_LEN * DIM;  // 8 MiB bf16 V^T (fragment-ordered)

  prep<<<1024, 256, 0, stream>>>(k, v, kb, vt);
  attn_fwd<<<1024, 256, 0, stream>>>(q, kb, vt, out);
}

// Round 4
// 136.580 us; speedup vs baseline: 2.9392x; 2.9392x over previous
//
#include <hip/hip_runtime.h>

#define S_LEN 2048
#define HEADS 16
#define DIM 64

typedef __attribute__((ext_vector_type(8))) short short8;
typedef __attribute__((ext_vector_type(16))) float float16v;
typedef __attribute__((ext_vector_type(4))) float float4v;
typedef __attribute__((ext_vector_type(4))) unsigned uint4v;

// packed fp32x2 -> bf16x2 (RNE), lo = first arg
static __device__ __forceinline__ unsigned pkbf(float lo, float hi) {
  unsigned r;
  asm("v_cvt_pk_bf16_f32 %0, %1, %2" : "=v"(r) : "v"(lo), "v"(hi));
  return r;
}

// ---------------- prep ----------------
// K: fp32 [bh][j][f] -> bf16, stored in MFMA-A-fragment order per 32-key tile:
//    kb[bh][jt][ks][hf][n][e]  (shorts: jt*2048 + ks*512 + hf*256 + n*8 + e)
//    holding K[jt*32+n][16ks+8hf+e] -- attn loads a tile as 4 contiguous 1KB chunks.
// V: fp32 [bh][j][f] -> bf16 V^T with bit2<->3 j-permute (matches P^T register
//    layout), stored fragment-ordered per 32-key tile:
//    vt[bh][jt][q=fh*2+kc][hf][n][e] holding V^T[f=fh*32+n][p=kc*16+8hf+e]
__global__ __launch_bounds__(256) void prep(const float* __restrict__ kk,
                                            const float* __restrict__ vv,
                                            short* __restrict__ kb,
                                            short* __restrict__ vt) {
  __shared__ unsigned t32[64 * 33];  // [f][p2] u32 = bf16 pair (p even, p odd)
  const int bx = blockIdx.x;
  const int bh = bx >> 5;
  const int j0 = (bx & 31) * 64;
  const int tid = threadIdx.x;

  // K convert -> fragment-ordered
  {
    const int j = tid >> 2, f0 = (tid & 3) * 16;
    const float4v* src = (const float4v*)(kk + ((size_t)bh * S_LEN + j0 + j) * DIM + f0);
    float4v a0 = src[0], a1 = src[1], a2 = src[2], a3 = src[3];
    uint4v w0, w1;
    w0[0] = pkbf(a0[0], a0[1]); w0[1] = pkbf(a0[2], a0[3]);
    w0[2] = pkbf(a1[0], a1[1]); w0[3] = pkbf(a1[2], a1[3]);
    w1[0] = pkbf(a2[0], a2[1]); w1[1] = pkbf(a2[2], a2[3]);
    w1[2] = pkbf(a3[0], a3[1]); w1[3] = pkbf(a3[2], a3[3]);
    short* dstb = kb + (size_t)bh * (S_LEN * DIM) +
                  ((j0 >> 5) + (j >> 5)) * 2048 + (f0 >> 4) * 512 + (j & 31) * 8;
    *(uint4v*)dstb = w0;            // hf = 0 chunk (f0..f0+7)
    *(uint4v*)(dstb + 256) = w1;    // hf = 1 chunk (f0+8..f0+15)
  }
  // V transpose + bit2<->3 permute; pack adjacent-j pairs
  {
    const int jp = (tid & 31) * 2, f0 = (tid >> 5) * 8;
    const int pp = ((jp & ~12) | ((jp & 4) << 1) | ((jp & 8) >> 1)) >> 1;
    const float* r0 = vv + ((size_t)bh * S_LEN + j0 + jp) * DIM + f0;
    const float* r1 = r0 + DIM;
    float4v a0 = *(const float4v*)r0, a1 = *(const float4v*)(r0 + 4);
    float4v b0 = *(const float4v*)r1, b1 = *(const float4v*)(r1 + 4);
#pragma unroll
    for (int e = 0; e < 4; e++) {
      t32[(f0 + e) * 33 + pp]     = pkbf(a0[e], b0[e]);
      t32[(f0 + 4 + e) * 33 + pp] = pkbf(a1[e], b1[e]);
    }
  }
  __syncthreads();
  {
    const int f = tid >> 2, x0 = (tid & 3) * 8;
    uint4v c0 = *(const uint4v*)&t32[f * 33 + x0];       // p = 2*x0 .. 2*x0+7  (hf=0)
    uint4v c1 = *(const uint4v*)&t32[f * 33 + x0 + 4];   // p = 2*x0+8 .. +15   (hf=1)
    const int jt = (j0 >> 5) + (x0 >> 4);
    const int qd = (f >> 5) * 2 + ((x0 >> 3) & 1);       // fh*2 + kc
    short* dstb = vt + (size_t)bh * (S_LEN * DIM) + jt * 2048 + qd * 512 + (f & 31) * 8;
    *(uint4v*)dstb = c0;
    *(uint4v*)(dstb + 256) = c1;
  }
}

// ---------------- fused attention: barrier-free 2-way j-split, 3 waves/SIMD ----------------
// grid 1024 = 32 bh * 32 i-tiles(64 rows); block 128 = 2 waves.
// Wave w handles ALL 64 i-rows (2 x 32-i MFMA tiles) for HALF the keys
// (j in [w*1024, w*1024+1024)), 32 iterations of 32-key tiles. No LDS/barriers in
// the main loop; K/V frags load straight global->VGPR from fragment-ordered tiles;
// register prefetch 1 tile ahead. launch_bounds(128,3): VGPR cap 170 >= ~160 live
// (no spill -- the (256,4) cap-64 spill disaster of the previous round), 6 blocks/CU
// = 3 waves/SIMD. LDS cut to 17.9 KB so it is not the binding constraint.
// Epilogue: i-tile ownership -- wave w owns i-tile w; partner sends the other tile.
__global__ __launch_bounds__(128, 3) void attn_fwd(const float* __restrict__ q,
                                                   const short* __restrict__ kb,
                                                   const short* __restrict__ vt,
                                                   float* __restrict__ out) {
  __shared__ alignas(16) float smem[4480];  // slot0[2176] | slot1[2176] | db[128] = 17.9KB
  const int bx0 = blockIdx.x;
  const int bx = (bx0 & 7) * 128 + (bx0 >> 3);  // XCD-chunked swizzle (bijective, 1024%8==0)
  const int bh = bx >> 5, it = bx & 31;
  const int b = bh >> 4, h = bh & 15;
  const int tid = threadIdx.x;
  const int w = tid >> 6, lane = tid & 63;
  const int n = lane & 31, hf = lane >> 5;
  const int i0 = it * 64;

  // Q B-frags for two i-tiles (cols i0+n and i0+32+n), scaled by log2e/8
  short8 qa0[4], qa1[4];
  {
    const float sc = 0.125f * 1.44269504088896f;
    const float* qr = q + ((size_t)bh * S_LEN + i0 + n) * DIM + hf * 8;
#pragma unroll
    for (int ks = 0; ks < 4; ks++) {
      float4v x0 = *(const float4v*)(qr + ks * 16);
      float4v x1 = *(const float4v*)(qr + ks * 16 + 4);
      uint4v pk_;
      pk_[0] = pkbf(x0[0] * sc, x0[1] * sc); pk_[1] = pkbf(x0[2] * sc, x0[3] * sc);
      pk_[2] = pkbf(x1[0] * sc, x1[1] * sc); pk_[3] = pkbf(x1[2] * sc, x1[3] * sc);
      qa0[ks] = *(short8*)&pk_;
      float4v y0 = *(const float4v*)(qr + 32 * DIM + ks * 16);
      float4v y1 = *(const float4v*)(qr + 32 * DIM + ks * 16 + 4);
      pk_[0] = pkbf(y0[0] * sc, y0[1] * sc); pk_[1] = pkbf(y0[2] * sc, y0[3] * sc);
      pk_[2] = pkbf(y1[0] * sc, y1[1] * sc); pk_[3] = pkbf(y1[2] * sc, y1[3] * sc);
      qa1[ks] = *(short8*)&pk_;
    }
  }

  // per-lane tile base pointers (this wave's j-half; tile = 2048 shorts = 4KB)
  const short* kp = kb + (size_t)bh * (S_LEN * DIM) + (size_t)w * (S_LEN * DIM / 2) + lane * 8;
  const short* vp = vt + (size_t)bh * (S_LEN * DIM) + (size_t)w * (S_LEN * DIM / 2) + lane * 8;

  short8 kf[4], vf[4];
#pragma unroll
  for (int u = 0; u < 4; u++) {
    kf[u] = *(const short8*)(kp + u * 512);
    vf[u] = *(const short8*)(vp + u * 512);
  }

  float16v zz;
#pragma unroll
  for (int e = 0; e < 16; e++) zz[e] = 0.f;
  float16v a00 = zz, a01 = zz, a10 = zz, a11 = zz;  // a[fh][itile] of O^T (unnormalized)
  float lpa0 = 0.f, lpb0 = 0.f, lpa1 = 0.f, lpb1 = 0.f;  // split add-chains

#pragma unroll 1
  for (int t = 0; t < 32; ++t) {
    const int adv = (t < 31) ? 2048 : 0;
    // S^T itile0 = K (Q0')^T, then exp/pack it BEFORE itile1 (halves st live range)
    __builtin_amdgcn_s_setprio(1);
    float16v st0 = __builtin_amdgcn_mfma_f32_32x32x16_bf16(kf[0], qa0[0], zz, 0, 0, 0);
#pragma unroll
    for (int ks = 1; ks < 4; ks++)
      st0 = __builtin_amdgcn_mfma_f32_32x32x16_bf16(kf[ks], qa0[ks], st0, 0, 0, 0);
    __builtin_amdgcn_s_setprio(0);
#pragma unroll
    for (int e = 0; e < 16; e++) st0[e] = __builtin_amdgcn_exp2f(st0[e]);
#pragma unroll
    for (int e = 0; e < 8; e++) { lpa0 += st0[2 * e]; lpb0 += st0[2 * e + 1]; }
    uint4v pb00, pb01;
#pragma unroll
    for (int u = 0; u < 4; u++) {
      pb00[u] = pkbf(st0[2 * u], st0[2 * u + 1]);
      pb01[u] = pkbf(st0[8 + 2 * u], st0[8 + 2 * u + 1]);
    }

    // S^T itile1
    __builtin_amdgcn_s_setprio(1);
    float16v st1 = __builtin_amdgcn_mfma_f32_32x32x16_bf16(kf[0], qa1[0], zz, 0, 0, 0);
#pragma unroll
    for (int ks = 1; ks < 4; ks++)
      st1 = __builtin_amdgcn_mfma_f32_32x32x16_bf16(kf[ks], qa1[ks], st1, 0, 0, 0);
    __builtin_amdgcn_s_setprio(0);
    // prefetch K(t+1) -- kf fully consumed; loads fly under exp/pack/PV
    kp += adv;
#pragma unroll
    for (int u = 0; u < 4; u++) kf[u] = *(const short8*)(kp + u * 512);

#pragma unroll
    for (int e = 0; e < 16; e++) st1[e] = __builtin_amdgcn_exp2f(st1[e]);
#pragma unroll
    for (int e = 0; e < 8; e++) { lpa1 += st1[2 * e]; lpb1 += st1[2 * e + 1]; }
    uint4v pb10, pb11;
#pragma unroll
    for (int u = 0; u < 4; u++) {
      pb10[u] = pkbf(st1[2 * u], st1[2 * u + 1]);
      pb11[u] = pkbf(st1[8 + 2 * u], st1[8 + 2 * u + 1]);
    }
    short8 p00 = *(short8*)&pb00, p01 = *(short8*)&pb01;
    short8 p10 = *(short8*)&pb10, p11 = *(short8*)&pb11;

    // O^T += V^T P^T  (vf[q]: q = fh*2+kc)
    __builtin_amdgcn_s_setprio(1);
    a00 = __builtin_amdgcn_mfma_f32_32x32x16_bf16(vf[0], p00, a00, 0, 0, 0);
    a00 = __builtin_amdgcn_mfma_f32_32x32x16_bf16(vf[1], p01, a00, 0, 0, 0);
    a01 = __builtin_amdgcn_mfma_f32_32x32x16_bf16(vf[0], p10, a01, 0, 0, 0);
    a01 = __builtin_amdgcn_mfma_f32_32x32x16_bf16(vf[1], p11, a01, 0, 0, 0);
    a10 = __builtin_amdgcn_mfma_f32_32x32x16_bf16(vf[2], p00, a10, 0, 0, 0);
    a10 = __builtin_amdgcn_mfma_f32_32x32x16_bf16(vf[3], p01, a10, 0, 0, 0);
    a11 = __builtin_amdgcn_mfma_f32_32x32x16_bf16(vf[2], p10, a11, 0, 0, 0);
    a11 = __builtin_amdgcn_mfma_f32_32x32x16_bf16(vf[3], p11, a11, 0, 0, 0);
    __builtin_amdgcn_s_setprio(0);
    // prefetch V(t+1)
    vp += adv;
#pragma unroll
    for (int u = 0; u < 4; u++) vf[u] = *(const short8*)(vp + u * 512);
  }

  // wave-local denominators (lanes n / n+32 hold complementary j rows of col i=n)
  float d0 = lpa0 + lpb0;
  float d1 = lpa1 + lpb1;
  d0 += __shfl_xor(d0, 32);
  d1 += __shfl_xor(d1, 32);

  // ---- epilogue: i-tile ownership (wave w owns i-tile w) ----
  float* const db = smem + 4352;  // [wave][itile][n]
  if (hf == 0) { db[w * 64 + n] = d0; db[w * 64 + 32 + n] = d1; }

  // send the NOT-owned i-tile's partials into the partner's slot
  {
    float* buf = smem + (1 - w) * 2176;
    float16v s0 = w ? a00 : a01;  // fh=0 partials of i-tile (1-w)
    float16v s1 = w ? a10 : a11;  // fh=1 partials
#pragma unroll
    for (int c = 0; c < 4; c++) {
      float4v u0, u1;
#pragma unroll
      for (int e = 0; e < 4; e++) { u0[e] = s0[4 * c + e]; u1[e] = s1[4 * c + e]; }
      *(float4v*)&buf[c * 256 + lane * 4] = u0;
      *(float4v*)&buf[1024 + c * 256 + lane * 4] = u1;
    }
  }
  __syncthreads();

  // combine into owned tile + normalize (held in regs across the next barrier)
  float16v o0 = w ? a01 : a00;  // fh=0 of owned i-tile
  float16v o1 = w ? a11 : a10;  // fh=1
  {
    const float dt = db[w * 32 + n] + db[64 + w * 32 + n];
    const float inv = 1.f / dt;
    const float* buf = smem + w * 2176;
#pragma unroll
    for (int c = 0; c < 4; c++) {
      float4v u0 = *(const float4v*)&buf[c * 256 + lane * 4];
      float4v u1 = *(const float4v*)&buf[1024 + c * 256 + lane * 4];
#pragma unroll
      for (int e = 0; e < 4; e++) {
        o0[4 * c + e] = (o0[4 * c + e] + u0[e]) * inv;
        o1[4 * c + e] = (o1[4 * c + e] + u1[e]) * inv;
      }
    }
  }
  __syncthreads();  // exchange reads complete before transpose overwrites slots

  // transpose own 32x64 tile via own slot ([32][68]), then coalesced store
  float* const tb = smem + w * 2176;
#pragma unroll
  for (int c = 0; c < 4; c++) {
    float4v u0, u1;
#pragma unroll
    for (int e = 0; e < 4; e++) { u0[e] = o0[4 * c + e]; u1[e] = o1[4 * c + e]; }
    *(float4v*)&tb[n * 68 + 8 * c + 4 * hf] = u0;        // f = 8c+4hf+e
    *(float4v*)&tb[n * 68 + 32 + 8 * c + 4 * hf] = u1;   // f = 32+8c+4hf+e
  }
  // same-wave LDS dependency only: compiler orders via lgkmcnt
  {
    const int il = lane >> 1, fq = (lane & 1) * 32;
    const float* src = &tb[il * 68 + fq];
    float* dst = out + (((size_t)b * S_LEN + i0 + w * 32 + il) * HEADS + h) * DIM + fq;
#pragma unroll
    for (int u = 0; u < 8; u++) ((float4v*)dst)[u] = ((const float4v*)src)[u];
  }
}

extern "C" void kernel_launch(void* const* d_in, const int* in_sizes, int n_in,
                              void* d_out, int out_size, void* d_ws, size_t ws_size,
                              hipStream_t stream) {
  const float* q = (const float*)d_in[0];
  const float* k = (const float*)d_in[1];
  const float* v = (const float*)d_in[2];
  float* out = (float*)d_out;
  short* kb = (short*)d_ws;                             // 8 MiB bf16 K (fragment-ordered)
  short* vt = (short*)d_ws + (size_t)32 * S_LEN * DIM;  // 8 MiB bf16 V^T (fragment-ordered)

  prep<<<1024, 256, 0, stream>>>(k, v, kb, vt);
  attn_fwd<<<1024, 128, 0, stream>>>(q, kb, vt, out);
}

// Round 5
// 133.888 us; speedup vs baseline: 2.9983x; 1.0201x over previous
//
#include <hip/hip_runtime.h>

#define S_LEN 2048
#define HEADS 16
#define DIM 64

typedef __attribute__((ext_vector_type(8))) short short8;
typedef __attribute__((ext_vector_type(16))) float float16v;
typedef __attribute__((ext_vector_type(4))) float float4v;
typedef __attribute__((ext_vector_type(4))) unsigned uint4v;

// packed fp32x2 -> bf16x2 (RNE), lo = first arg
static __device__ __forceinline__ unsigned pkbf(float lo, float hi) {
  unsigned r;
  asm("v_cvt_pk_bf16_f32 %0, %1, %2" : "=v"(r) : "v"(lo), "v"(hi));
  return r;
}

// ---------------- prep ----------------
// K: fp32 [bh][j][f] -> bf16, stored in MFMA-A-fragment order per 32-key tile:
//    kb[bh][jt][ks][hf][n][e]  (shorts: jt*2048 + ks*512 + hf*256 + n*8 + e)
//    holding K[jt*32+n][16ks+8hf+e] -- attn loads a tile as 4 contiguous 1KB chunks.
// V: fp32 [bh][j][f] -> bf16 V^T with bit2<->3 j-permute (matches P^T register
//    layout), stored fragment-ordered per 32-key tile:
//    vt[bh][jt][q=fh*2+kc][hf][n][e] holding V^T[f=fh*32+n][p=kc*16+8hf+e]
__global__ __launch_bounds__(256) void prep(const float* __restrict__ kk,
                                            const float* __restrict__ vv,
                                            short* __restrict__ kb,
                                            short* __restrict__ vt) {
  __shared__ unsigned t32[64 * 33];  // [f][p2] u32 = bf16 pair (p even, p odd)
  const int bx = blockIdx.x;
  const int bh = bx >> 5;
  const int j0 = (bx & 31) * 64;
  const int tid = threadIdx.x;

  // K convert -> fragment-ordered
  {
    const int j = tid >> 2, f0 = (tid & 3) * 16;
    const float4v* src = (const float4v*)(kk + ((size_t)bh * S_LEN + j0 + j) * DIM + f0);
    float4v a0 = src[0], a1 = src[1], a2 = src[2], a3 = src[3];
    uint4v w0, w1;
    w0[0] = pkbf(a0[0], a0[1]); w0[1] = pkbf(a0[2], a0[3]);
    w0[2] = pkbf(a1[0], a1[1]); w0[3] = pkbf(a1[2], a1[3]);
    w1[0] = pkbf(a2[0], a2[1]); w1[1] = pkbf(a2[2], a2[3]);
    w1[2] = pkbf(a3[0], a3[1]); w1[3] = pkbf(a3[2], a3[3]);
    short* dstb = kb + (size_t)bh * (S_LEN * DIM) +
                  ((j0 >> 5) + (j >> 5)) * 2048 + (f0 >> 4) * 512 + (j & 31) * 8;
    *(uint4v*)dstb = w0;            // hf = 0 chunk (f0..f0+7)
    *(uint4v*)(dstb + 256) = w1;    // hf = 1 chunk (f0+8..f0+15)
  }
  // V transpose + bit2<->3 permute; pack adjacent-j pairs
  {
    const int jp = (tid & 31) * 2, f0 = (tid >> 5) * 8;
    const int pp = ((jp & ~12) | ((jp & 4) << 1) | ((jp & 8) >> 1)) >> 1;
    const float* r0 = vv + ((size_t)bh * S_LEN + j0 + jp) * DIM + f0;
    const float* r1 = r0 + DIM;
    float4v a0 = *(const float4v*)r0, a1 = *(const float4v*)(r0 + 4);
    float4v b0 = *(const float4v*)r1, b1 = *(const float4v*)(r1 + 4);
#pragma unroll
    for (int e = 0; e < 4; e++) {
      t32[(f0 + e) * 33 + pp]     = pkbf(a0[e], b0[e]);
      t32[(f0 + 4 + e) * 33 + pp] = pkbf(a1[e], b1[e]);
    }
  }
  __syncthreads();
  {
    const int f = tid >> 2, x0 = (tid & 3) * 8;
    uint4v c0 = *(const uint4v*)&t32[f * 33 + x0];       // p = 2*x0 .. 2*x0+7  (hf=0)
    uint4v c1 = *(const uint4v*)&t32[f * 33 + x0 + 4];   // p = 2*x0+8 .. +15   (hf=1)
    const int jt = (j0 >> 5) + (x0 >> 4);
    const int qd = (f >> 5) * 2 + ((x0 >> 3) & 1);       // fh*2 + kc
    short* dstb = vt + (size_t)bh * (S_LEN * DIM) + jt * 2048 + qd * 512 + (f & 31) * 8;
    *(uint4v*)dstb = c0;
    *(uint4v*)(dstb + 256) = c1;
  }
}

// ---------------- fused attention: barrier-free 4-way j-split ----------------
// grid 1024 = 32 bh * 32 i-tiles(64 rows); block 256 = 4 waves.
// Wave w handles ALL 64 i-rows for a QUARTER of the keys (j in [w*512, w*512+512)),
// 16 iterations of 32-key tiles. No LDS/barriers in the main loop; K/V frags load
// straight global->VGPR from fragment-ordered tiles; register prefetch 1 tile ahead.
// launch_bounds(256,3): VGPR cap 170 >= ~148 live (NOT (256,4) -- that forced cap 64
// and a 835MB spill catastrophe) -> 3 blocks/CU = 12 waves/CU = 3 waves/SIMD.
// Occupancy was GRID-capped at 8 waves/CU with 128-thread blocks; 4-wave blocks
// raise the grid cap to 16 and regs allow 12.
// Epilogue: 3-round ring reduction of quadrant partials + denom combine via LDS.
__global__ __launch_bounds__(256, 3) void attn_fwd(const float* __restrict__ q,
                                                   const short* __restrict__ kb,
                                                   const short* __restrict__ vt,
                                                   float* __restrict__ out) {
  __shared__ alignas(16) float smem[4 * 1056 + 256];  // 4 slots (ring/transpose) + denom = 17.9KB
  const int bx0 = blockIdx.x;
  const int bx = (bx0 & 7) * 128 + (bx0 >> 3);  // XCD-chunked swizzle (bijective, 1024%8==0)
  const int bh = bx >> 5, it = bx & 31;
  const int b = bh >> 4, h = bh & 15;
  const int tid = threadIdx.x;
  const int w = tid >> 6, lane = tid & 63;
  const int n = lane & 31, hf = lane >> 5;
  const int i0 = it * 64;

  // Q B-frags for two i-tiles (cols i0+n and i0+32+n), scaled by log2e/8
  short8 qa0[4], qa1[4];
  {
    const float sc = 0.125f * 1.44269504088896f;
    const float* qr = q + ((size_t)bh * S_LEN + i0 + n) * DIM + hf * 8;
#pragma unroll
    for (int ks = 0; ks < 4; ks++) {
      float4v x0 = *(const float4v*)(qr + ks * 16);
      float4v x1 = *(const float4v*)(qr + ks * 16 + 4);
      uint4v pk_;
      pk_[0] = pkbf(x0[0] * sc, x0[1] * sc); pk_[1] = pkbf(x0[2] * sc, x0[3] * sc);
      pk_[2] = pkbf(x1[0] * sc, x1[1] * sc); pk_[3] = pkbf(x1[2] * sc, x1[3] * sc);
      qa0[ks] = *(short8*)&pk_;
      float4v y0 = *(const float4v*)(qr + 32 * DIM + ks * 16);
      float4v y1 = *(const float4v*)(qr + 32 * DIM + ks * 16 + 4);
      pk_[0] = pkbf(y0[0] * sc, y0[1] * sc); pk_[1] = pkbf(y0[2] * sc, y0[3] * sc);
      pk_[2] = pkbf(y1[0] * sc, y1[1] * sc); pk_[3] = pkbf(y1[2] * sc, y1[3] * sc);
      qa1[ks] = *(short8*)&pk_;
    }
  }

  // per-lane tile base pointers (this wave's j-quarter; tile = 2048 shorts = 4KB)
  const short* kp = kb + (size_t)bh * (S_LEN * DIM) + (size_t)w * (S_LEN * DIM / 4) + lane * 8;
  const short* vp = vt + (size_t)bh * (S_LEN * DIM) + (size_t)w * (S_LEN * DIM / 4) + lane * 8;

  short8 kf[4], vf[4];
#pragma unroll
  for (int u = 0; u < 4; u++) {
    kf[u] = *(const short8*)(kp + u * 512);
    vf[u] = *(const short8*)(vp + u * 512);
  }

  float16v zz;
#pragma unroll
  for (int e = 0; e < 16; e++) zz[e] = 0.f;
  float16v a00 = zz, a01 = zz, a10 = zz, a11 = zz;  // a[fh][itile] of O^T (unnormalized)
  float lpa0 = 0.f, lpb0 = 0.f, lpa1 = 0.f, lpb1 = 0.f;  // split add-chains

#pragma unroll 1
  for (int t = 0; t < 16; ++t) {
    const int adv = (t < 15) ? 2048 : 0;
    // S^T itile0 = K (Q0')^T, exp/pack BEFORE itile1 (halves st live range)
    __builtin_amdgcn_s_setprio(1);
    float16v st0 = __builtin_amdgcn_mfma_f32_32x32x16_bf16(kf[0], qa0[0], zz, 0, 0, 0);
#pragma unroll
    for (int ks = 1; ks < 4; ks++)
      st0 = __builtin_amdgcn_mfma_f32_32x32x16_bf16(kf[ks], qa0[ks], st0, 0, 0, 0);
    __builtin_amdgcn_s_setprio(0);
#pragma unroll
    for (int e = 0; e < 16; e++) st0[e] = __builtin_amdgcn_exp2f(st0[e]);
#pragma unroll
    for (int e = 0; e < 8; e++) { lpa0 += st0[2 * e]; lpb0 += st0[2 * e + 1]; }
    uint4v pb00, pb01;
#pragma unroll
    for (int u = 0; u < 4; u++) {
      pb00[u] = pkbf(st0[2 * u], st0[2 * u + 1]);
      pb01[u] = pkbf(st0[8 + 2 * u], st0[8 + 2 * u + 1]);
    }

    // S^T itile1
    __builtin_amdgcn_s_setprio(1);
    float16v st1 = __builtin_amdgcn_mfma_f32_32x32x16_bf16(kf[0], qa1[0], zz, 0, 0, 0);
#pragma unroll
    for (int ks = 1; ks < 4; ks++)
      st1 = __builtin_amdgcn_mfma_f32_32x32x16_bf16(kf[ks], qa1[ks], st1, 0, 0, 0);
    __builtin_amdgcn_s_setprio(0);
    // prefetch K(t+1) -- kf fully consumed; loads fly under exp/pack/PV
    kp += adv;
#pragma unroll
    for (int u = 0; u < 4; u++) kf[u] = *(const short8*)(kp + u * 512);

#pragma unroll
    for (int e = 0; e < 16; e++) st1[e] = __builtin_amdgcn_exp2f(st1[e]);
#pragma unroll
    for (int e = 0; e < 8; e++) { lpa1 += st1[2 * e]; lpb1 += st1[2 * e + 1]; }
    uint4v pb10, pb11;
#pragma unroll
    for (int u = 0; u < 4; u++) {
      pb10[u] = pkbf(st1[2 * u], st1[2 * u + 1]);
      pb11[u] = pkbf(st1[8 + 2 * u], st1[8 + 2 * u + 1]);
    }
    short8 p00 = *(short8*)&pb00, p01 = *(short8*)&pb01;
    short8 p10 = *(short8*)&pb10, p11 = *(short8*)&pb11;

    // O^T += V^T P^T  (vf[q]: q = fh*2+kc)
    __builtin_amdgcn_s_setprio(1);
    a00 = __builtin_amdgcn_mfma_f32_32x32x16_bf16(vf[0], p00, a00, 0, 0, 0);
    a00 = __builtin_amdgcn_mfma_f32_32x32x16_bf16(vf[1], p01, a00, 0, 0, 0);
    a01 = __builtin_amdgcn_mfma_f32_32x32x16_bf16(vf[0], p10, a01, 0, 0, 0);
    a01 = __builtin_amdgcn_mfma_f32_32x32x16_bf16(vf[1], p11, a01, 0, 0, 0);
    a10 = __builtin_amdgcn_mfma_f32_32x32x16_bf16(vf[2], p00, a10, 0, 0, 0);
    a10 = __builtin_amdgcn_mfma_f32_32x32x16_bf16(vf[3], p01, a10, 0, 0, 0);
    a11 = __builtin_amdgcn_mfma_f32_32x32x16_bf16(vf[2], p10, a11, 0, 0, 0);
    a11 = __builtin_amdgcn_mfma_f32_32x32x16_bf16(vf[3], p11, a11, 0, 0, 0);
    __builtin_amdgcn_s_setprio(0);
    // prefetch V(t+1)
    vp += adv;
#pragma unroll
    for (int u = 0; u < 4; u++) vf[u] = *(const short8*)(vp + u * 512);
  }

  // wave-local denominator (lanes n / n+32 hold complementary j rows of col i=n)
  float d0 = lpa0 + lpb0;
  float d1 = lpa1 + lpb1;
  d0 += __shfl_xor(d0, 32);
  d1 += __shfl_xor(d1, 32);

  // ---- cross-wave combine: quadrant q = itile*2 + fh, wave w owns quadrant w ----
  // partials: q0=a00 (it0,fh0)  q1=a10 (it0,fh1)  q2=a01 (it1,fh0)  q3=a11 (it1,fh1)
  float* const slots = smem;              // 4 x 1056 floats (ring exchange, then transpose)
  float* const db = smem + 4 * 1056;      // [wave][itile][n] denominators

  db[w * 64 + n] = d0;
  db[w * 64 + 32 + n] = d1;

  float16v own = (w == 0) ? a00 : (w == 1) ? a10 : (w == 2) ? a01 : a11;
#pragma unroll
  for (int r = 1; r < 4; r++) {
    const int s = (w + r) & 3;
    float16v snd = (s == 0) ? a00 : (s == 1) ? a10 : (s == 2) ? a01 : a11;
    float* sl = slots + w * 1056;
#pragma unroll
    for (int c = 0; c < 4; c++) {
      float4v u;
#pragma unroll
      for (int e = 0; e < 4; e++) u[e] = snd[4 * c + e];
      *(float4v*)&sl[c * 256 + lane * 4] = u;
    }
    __syncthreads();
    const float* rl = slots + ((w - r) & 3) * 1056;
#pragma unroll
    for (int c = 0; c < 4; c++) {
      float4v u = *(const float4v*)&rl[c * 256 + lane * 4];
#pragma unroll
      for (int e = 0; e < 4; e++) own[4 * c + e] += u[e];
    }
    __syncthreads();
  }

  // total denominator for this wave's quadrant (itile = w>>1), column i = n
  const int myit = w >> 1;
  const float dt = db[myit * 32 + n] + db[64 + myit * 32 + n] +
                   db[128 + myit * 32 + n] + db[192 + myit * 32 + n];
  const float inv = 1.f / dt;

  // normalize + transpose own quadrant via per-wave LDS region, then store
  float* const tb = slots + w * 1056;  // [i_local][f_local] stride 33
#pragma unroll
  for (int c = 0; c < 4; c++) {
    float4v u;
#pragma unroll
    for (int e = 0; e < 4; e++) u[e] = own[4 * c + e] * inv;
    *(float4v*)&tb[n * 33 + 8 * c + 4 * hf] = u;  // f_local = 8c + 4hf + e
  }
  // within-wave LDS dependency only (disjoint per-wave regions): compiler inserts lgkmcnt
  {
    const int il = lane >> 1, fq2 = (lane & 1) * 16;
    const float* src = &tb[il * 33 + fq2];
    float* dst = out + (((size_t)b * S_LEN + i0 + myit * 32 + il) * HEADS + h) * DIM +
                 (w & 1) * 32 + fq2;
#pragma unroll
    for (int u = 0; u < 4; u++) ((float4v*)dst)[u] = ((const float4v*)src)[u];
  }
}

extern "C" void kernel_launch(void* const* d_in, const int* in_sizes, int n_in,
                              void* d_out, int out_size, void* d_ws, size_t ws_size,
                              hipStream_t stream) {
  const float* q = (const float*)d_in[0];
  const float* k = (const float*)d_in[1];
  const float* v = (const float*)d_in[2];
  float* out = (float*)d_out;
  short* kb = (short*)d_ws;                             // 8 MiB bf16 K (fragment-ordered)
  short* vt = (short*)d_ws + (size_t)32 * S_LEN * DIM;  // 8 MiB bf16 V^T (fragment-ordered)

  prep<<<1024, 256, 0, stream>>>(k, v, kb, vt);
  attn_fwd<<<1024, 256, 0, stream>>>(q, kb, vt, out);
}